// Round 9
// baseline (216.177 us; speedup 1.0000x reference)
//
#include <hip/hip_runtime.h>
#include <math.h>

#define NNODES 100000
#define NEDGES 1600000
#define DD 128
#define BN_EPS 1e-5f

#define NBUCK 98     // ceil(100000/1024)
#define BUCKW 1024   // dsts per bucket (bucket = dst>>10)
#define PBLK 512     // partition blocks
#define PCHUNK 3125  // edges per partition block (512*3125 = 1.6M exact)
#define NTILES 1563  // ceil(100000/64) 64-row MLP tiles
#define FMM_GRID 512

typedef __attribute__((ext_vector_type(8))) short bf16x8;
typedef __attribute__((ext_vector_type(4))) float f32x4;
typedef __attribute__((ext_vector_type(2))) unsigned u32x2;
typedef __attribute__((ext_vector_type(4))) unsigned u32x4;

__device__ __forceinline__ unsigned short f2bf(float f) {  // RNE f32->bf16
  unsigned u = __builtin_bit_cast(unsigned, f);
  u = (u + 0x7fffu + ((u >> 16) & 1u)) >> 16;
  return (unsigned short)u;
}
__device__ __forceinline__ float bfLO(unsigned u) {
  return __builtin_bit_cast(float, u << 16);
}
__device__ __forceinline__ float bfHI(unsigned u) {
  return __builtin_bit_cast(float, u & 0xffff0000u);
}

// ---------------------------------------------------------------------------
// ws layout:
//   xb   [100000][128] bf16   25.6 MB
//   h0b  [100000][128] bf16   (agg; overwritten in-place by h2 in k_fmm)
//   (spare 25.6MB region)
//   rowPtr[100004] | edgeSrc[1.6M] | stage[1.6M] | cnt[98*512] | off[98*512]
//   bucketTot[128] | (pad 128) | wt1[16384] wt2[16384] (bf16) | bnSum/bnSq
// ---------------------------------------------------------------------------

// K1: fused prep. blocks 0-1: W->bf16 transposed+swizzled + zero bn.
// blocks 2..6251: x->bf16. blocks 6252..6763: per-(block,bucket) histogram.
__global__ __launch_bounds__(256) void k_prep(const float* __restrict__ x,
                                              const float* __restrict__ W1,
                                              const float* __restrict__ W2,
                                              unsigned short* __restrict__ xb,
                                              unsigned short* __restrict__ wt1,
                                              unsigned short* __restrict__ wt2,
                                              float* __restrict__ bnAcc,
                                              const int* __restrict__ e32,
                                              int* __restrict__ cnt) {
  __shared__ int sc[NBUCK];
  int bid = blockIdx.x, tid = threadIdx.x;
  if (bid < 2) {
    const float* W = bid ? W2 : W1;
    unsigned short* wt = bid ? wt2 : wt1;
    if (tid < 128) {
      int n = tid;
      for (int k = 0; k < 128; ++k)
        wt[n * 128 + (k ^ ((n & 7) << 3))] = f2bf(W[k * 128 + n]);
    } else {
      bnAcc[(bid ? 0 : 128) + (tid - 128)] = 0.f;  // bnSum / bnSq halves
    }
  } else if (bid < 6252) {  // x -> bf16 : 6250 blocks * 2048 elems
    long j = (long)(bid - 2) * 2048 + tid * 8;
    f32x4 a = __builtin_nontemporal_load((const f32x4*)(x + j));
    f32x4 b = __builtin_nontemporal_load((const f32x4*)(x + j + 4));
    u32x4 o;
    o.x = (unsigned)f2bf(a.x) | ((unsigned)f2bf(a.y) << 16);
    o.y = (unsigned)f2bf(a.z) | ((unsigned)f2bf(a.w) << 16);
    o.z = (unsigned)f2bf(b.x) | ((unsigned)f2bf(b.y) << 16);
    o.w = (unsigned)f2bf(b.z) | ((unsigned)f2bf(b.w) << 16);
    *(u32x4*)(xb + j) = o;
  } else {  // pcount
    int blk = bid - 6252;
    int z = (tid < 64) ? (e32[2 * tid + 1] == 0) : 1;
    int is64 = __syncthreads_and(z);
    for (int i = tid; i < NBUCK; i += 256) sc[i] = 0;
    __syncthreads();
    const int* dstp = is64 ? (e32 + 2 * (long)NEDGES) : (e32 + NEDGES);
    long e0 = (long)blk * PCHUNK;
    for (int i = tid; i < PCHUNK; i += 256) {
      long e = e0 + i;
      int d = is64 ? dstp[2 * e] : dstp[e];
      atomicAdd(&sc[d >> 10], 1);
    }
    __syncthreads();
    for (int i = tid; i < NBUCK; i += 256) cnt[i * PBLK + blk] = sc[i];
  }
}

// K2: per-bucket local scan of 512 block counts -> off (local), bucketTot.
__global__ __launch_bounds__(256) void k_lscan(const int* __restrict__ cnt,
                                               int* __restrict__ off,
                                               int* __restrict__ bucketTot) {
  __shared__ int s[256];
  int b = blockIdx.x, tid = threadIdx.x;
  int v0 = cnt[b * PBLK + 2 * tid], v1 = cnt[b * PBLK + 2 * tid + 1];
  s[tid] = v0 + v1;
  __syncthreads();
  for (int o = 1; o < 256; o <<= 1) {
    int v = (tid >= o) ? s[tid - o] : 0;
    __syncthreads();
    s[tid] += v;
    __syncthreads();
  }
  int excl = s[tid] - v0 - v1;
  off[b * PBLK + 2 * tid] = excl;
  off[b * PBLK + 2 * tid + 1] = excl + v0;
  if (tid == 255) bucketTot[b] = s[255];
}

// K3: partition edges into bucket-major stage, packed (src<<10)|dstLocal.
// Inlines the bucketBase exclusive scan (98 values, cheap per block).
__global__ __launch_bounds__(256) void k_ppart(const int* __restrict__ e32,
                                               const int* __restrict__ off,
                                               const int* __restrict__ bucketTot,
                                               unsigned* __restrict__ stage) {
  __shared__ int cur[NBUCK];
  __shared__ int sbase[128];
  int tid = threadIdx.x, blk = blockIdx.x;
  int z = (tid < 64) ? (e32[2 * tid + 1] == 0) : 1;
  int is64 = __syncthreads_and(z);
  if (tid < 128) sbase[tid] = (tid < NBUCK) ? bucketTot[tid] : 0;
  __syncthreads();
  for (int o = 1; o < 128; o <<= 1) {
    int v = (tid >= o && tid < 128) ? sbase[tid - o] : 0;
    __syncthreads();
    if (tid < 128) sbase[tid] += v;
    __syncthreads();
  }
  if (tid < NBUCK)
    cur[tid] = off[tid * PBLK + blk] + ((tid == 0) ? 0 : sbase[tid - 1]);
  __syncthreads();
  const int* dstp = is64 ? (e32 + 2 * (long)NEDGES) : (e32 + NEDGES);
  long e0 = (long)blk * PCHUNK;
  for (int i = tid; i < PCHUNK; i += 256) {
    long e = e0 + i;
    int d = is64 ? dstp[2 * e] : dstp[e];
    int sv = is64 ? e32[2 * e] : e32[e];
    int pos = atomicAdd(&cur[d >> 10], 1);
    stage[pos] = ((unsigned)sv << 10) | (unsigned)(d & (BUCKW - 1));
  }
}

// K4: one block per bucket: LDS histogram -> scan -> rowPtr; place edgeSrc.
// Inlines bucketBase scan; block 0 sets rowPtr[NNODES].
__global__ __launch_bounds__(256) void k_bucket(const unsigned* __restrict__ stage,
                                                const int* __restrict__ bucketTot,
                                                int* __restrict__ rowPtr,
                                                int* __restrict__ edgeSrc) {
  __shared__ int sdeg[BUCKW];
  __shared__ int srow[BUCKW];
  __shared__ int ss[256];
  __shared__ int sbase[128];
  int b = blockIdx.x, tid = threadIdx.x;
  if (tid < 128) sbase[tid] = (tid < NBUCK) ? bucketTot[tid] : 0;
  for (int i = tid; i < BUCKW; i += 256) sdeg[i] = 0;
  __syncthreads();
  for (int o = 1; o < 128; o <<= 1) {
    int v = (tid >= o && tid < 128) ? sbase[tid - o] : 0;
    __syncthreads();
    if (tid < 128) sbase[tid] += v;
    __syncthreads();
  }
  int base = (b == 0) ? 0 : sbase[b - 1];
  int tot = bucketTot[b];
  if (b == 0 && tid == 0) rowPtr[NNODES] = NEDGES;
  const unsigned* st = stage + base;
  for (int i = tid; i < tot; i += 256) atomicAdd(&sdeg[st[i] & (BUCKW - 1)], 1);
  __syncthreads();
  int j = tid * 4;
  int d0 = sdeg[j], d1 = sdeg[j + 1], d2 = sdeg[j + 2], d3 = sdeg[j + 3];
  int tsum = d0 + d1 + d2 + d3;
  ss[tid] = tsum;
  __syncthreads();
  for (int o = 1; o < 256; o <<= 1) {
    int v = (tid >= o) ? ss[tid - o] : 0;
    __syncthreads();
    ss[tid] += v;
    __syncthreads();
  }
  int excl = ss[tid] - tsum;
  srow[j] = excl;
  srow[j + 1] = excl + d0;
  srow[j + 2] = excl + d0 + d1;
  srow[j + 3] = excl + d0 + d1 + d2;
  __syncthreads();
  for (int i = tid; i < BUCKW; i += 256) {
    int dst = b * BUCKW + i;
    if (dst < NNODES) rowPtr[dst] = base + srow[i];
    sdeg[i] = srow[i];  // reuse as cursor
  }
  __syncthreads();
  for (int i = tid; i < tot; i += 256) {
    unsigned p = st[i];
    int pos = atomicAdd(&sdeg[p & (BUCKW - 1)], 1);
    edgeSrc[base + pos] = (int)(p >> 10);
  }
}

// K5: gather at 8B/lane. Wave = 1 node; lanes 0-31 edge e, lanes 32-63 e+1.
// NT hints: edgeSrc streamed once; h0b not re-read soon -> keep xb hot in L2.
__global__ __launch_bounds__(256) void k_gather(const u32x2* __restrict__ xb2,
                                                const int* __restrict__ rowPtr,
                                                const int* __restrict__ edgeSrc,
                                                u32x2* __restrict__ h0b2) {
  int node = (blockIdx.x * 256 + threadIdx.x) >> 6;
  int lane = threadIdx.x & 63;
  if (node >= NNODES) return;
  int li = lane & 31, half = lane >> 5;
  int beg = rowPtr[node], end = rowPtr[node + 1];
  float a0 = 0.f, a1 = 0.f, a2 = 0.f, a3 = 0.f;
  if (half == 0) {  // init from own row
    u32x2 u = xb2[(long)node * 32 + li];
    a0 = bfLO(u.x); a1 = bfHI(u.x); a2 = bfLO(u.y); a3 = bfHI(u.y);
  }
  int e = beg;
  for (; e + 4 <= end; e += 4) {
    int sA_ = __builtin_nontemporal_load(edgeSrc + e + half);
    int sB_ = __builtin_nontemporal_load(edgeSrc + e + 2 + half);
    u32x2 va = xb2[(long)sA_ * 32 + li];
    u32x2 vb = xb2[(long)sB_ * 32 + li];
    a0 += bfLO(va.x); a1 += bfHI(va.x); a2 += bfLO(va.y); a3 += bfHI(va.y);
    a0 += bfLO(vb.x); a1 += bfHI(vb.x); a2 += bfLO(vb.y); a3 += bfHI(vb.y);
  }
  if (e + 2 <= end) {
    int s_ = __builtin_nontemporal_load(edgeSrc + e + half);
    u32x2 v = xb2[(long)s_ * 32 + li];
    a0 += bfLO(v.x); a1 += bfHI(v.x); a2 += bfLO(v.y); a3 += bfHI(v.y);
    e += 2;
  }
  if (e < end && half == 0) {  // odd tail: lower half only
    int s_ = edgeSrc[e];
    u32x2 v = xb2[(long)s_ * 32 + li];
    a0 += bfLO(v.x); a1 += bfHI(v.x); a2 += bfLO(v.y); a3 += bfHI(v.y);
  }
  a0 += __shfl_xor(a0, 32, 64);
  a1 += __shfl_xor(a1, 32, 64);
  a2 += __shfl_xor(a2, 32, 64);
  a3 += __shfl_xor(a3, 32, 64);
  if (half == 0) {
    u32x2 o;
    o.x = (unsigned)f2bf(a0) | ((unsigned)f2bf(a1) << 16);
    o.y = (unsigned)f2bf(a2) | ((unsigned)f2bf(a3) << 16);
    __builtin_nontemporal_store(o, h0b2 + (long)node * 32 + li);
  }
}

// K6: PERSISTENT fused MLP. 512 blocks x 256 thr (2 blocks/CU @ 80KB LDS).
// W1+W2 staged ONCE per block; grid-stride over 1563 64-row tiles.
// Per tile: A from global (NT) -> GEMM1 -> relu+b1 -> swizzled LDS h1 tile ->
// (prefetch next A) -> GEMM2 -> h2 store (NT, in-place over h0b) + BN in regs.
// 4 waves; wave w owns rows [w*16, w*16+16) x all 128 cols of the tile.
__global__ __launch_bounds__(256) void k_fmm(const unsigned short* Ab,
                                             const unsigned short* __restrict__ Wt1,
                                             const unsigned short* __restrict__ Wt2,
                                             const float* __restrict__ b1,
                                             const float* __restrict__ b2,
                                             unsigned short* Cb,
                                             float* __restrict__ bnSum,
                                             float* __restrict__ bnSq) {
  __shared__ __align__(16) char smem[81920];
  unsigned short* sW1 = (unsigned short*)smem;           // 32 KB
  unsigned short* sW2 = (unsigned short*)(smem + 32768); // 32 KB
  unsigned short* sH  = (unsigned short*)(smem + 65536); // 16 KB h1 tile
  float* sbn = (float*)(smem + 65536);                   // aliases sH
  int tid = threadIdx.x;
#pragma unroll
  for (int i = 0; i < 8; ++i) {
    ((u32x4*)sW1)[tid + 256 * i] = ((const u32x4*)Wt1)[tid + 256 * i];
    ((u32x4*)sW2)[tid + 256 * i] = ((const u32x4*)Wt2)[tid + 256 * i];
  }
  int w = tid >> 6, lane = tid & 63, l4 = lane >> 4, l15 = lane & 15;
  float bb1[8], bb2[8], ls[8], lq[8];
#pragma unroll
  for (int ni = 0; ni < 8; ++ni) {
    bb1[ni] = b1[ni * 16 + l15];
    bb2[ni] = b2[ni * 16 + l15];
    ls[ni] = 0.f; lq[ni] = 0.f;
  }

  int tile = blockIdx.x;
  bf16x8 af[4];
  {
    int r = tile * 64 + w * 16 + l15;
    if (r > NNODES - 1) r = NNODES - 1;
#pragma unroll
    for (int ks = 0; ks < 4; ++ks)
      af[ks] = __builtin_nontemporal_load(
          (const bf16x8*)(Ab + (long)r * 128 + ks * 32 + l4 * 8));
  }
  __syncthreads();  // W staged

  while (tile < NTILES) {
    int next = tile + FMM_GRID;
    f32x4 acc[8];
#pragma unroll
    for (int ni = 0; ni < 8; ++ni) acc[ni] = (f32x4){0.f, 0.f, 0.f, 0.f};
#pragma unroll
    for (int ks = 0; ks < 4; ++ks)
#pragma unroll
      for (int ni = 0; ni < 8; ++ni) {
        int n = ni * 16 + l15, k = ks * 32 + l4 * 8;
        bf16x8 bf = *(const bf16x8*)(sW1 + n * 128 + (k ^ ((n & 7) << 3)));
        acc[ni] = __builtin_amdgcn_mfma_f32_16x16x32_bf16(af[ks], bf, acc[ni], 0, 0, 0);
      }
    __syncthreads();  // prior iteration's sH readers done -> writable
#pragma unroll
    for (int ni = 0; ni < 8; ++ni) {
      int col = ni * 16 + l15;
#pragma unroll
      for (int rr = 0; rr < 4; ++rr) {
        int row = w * 16 + l4 * 4 + rr;
        float v = fmaxf(acc[ni][rr] + bb1[ni], 0.f);
        sH[row * 128 + (col ^ ((row & 7) << 3))] = f2bf(v);
      }
    }
    __syncthreads();
    bf16x8 afn[4] = {af[0], af[1], af[2], af[3]};
    if (next < NTILES) {  // prefetch next tile's A (overlaps GEMM2)
      int r = next * 64 + w * 16 + l15;
      if (r > NNODES - 1) r = NNODES - 1;
#pragma unroll
      for (int ks = 0; ks < 4; ++ks)
        afn[ks] = __builtin_nontemporal_load(
            (const bf16x8*)(Ab + (long)r * 128 + ks * 32 + l4 * 8));
    }
    bf16x8 a2[4];
    {
      int row = w * 16 + l15;
#pragma unroll
      for (int ks = 0; ks < 4; ++ks) {
        int k = ks * 32 + l4 * 8;
        a2[ks] = *(const bf16x8*)(sH + row * 128 + (k ^ ((row & 7) << 3)));
      }
    }
#pragma unroll
    for (int ni = 0; ni < 8; ++ni) acc[ni] = (f32x4){0.f, 0.f, 0.f, 0.f};
#pragma unroll
    for (int ks = 0; ks < 4; ++ks)
#pragma unroll
      for (int ni = 0; ni < 8; ++ni) {
        int n = ni * 16 + l15, k = ks * 32 + l4 * 8;
        bf16x8 bf = *(const bf16x8*)(sW2 + n * 128 + (k ^ ((n & 7) << 3)));
        acc[ni] = __builtin_amdgcn_mfma_f32_16x16x32_bf16(a2[ks], bf, acc[ni], 0, 0, 0);
      }
#pragma unroll
    for (int ni = 0; ni < 8; ++ni) {
      int n = ni * 16 + l15;
#pragma unroll
      for (int rr = 0; rr < 4; ++rr) {
        int row = tile * 64 + w * 16 + l4 * 4 + rr;
        if (row < NNODES) {
          float v = acc[ni][rr] + bb2[ni];
          __builtin_nontemporal_store(f2bf(v), Cb + (long)row * 128 + n);
          ls[ni] += v; lq[ni] += v * v;
        }
      }
    }
#pragma unroll
    for (int ks = 0; ks < 4; ++ks) af[ks] = afn[ks];
    tile = next;
  }

  // BN: reduce reg partials (cols fixed per thread) -> LDS -> global atomics.
#pragma unroll
  for (int j = 0; j < 8; ++j) {
    ls[j] += __shfl_xor(ls[j], 16, 64); ls[j] += __shfl_xor(ls[j], 32, 64);
    lq[j] += __shfl_xor(lq[j], 16, 64); lq[j] += __shfl_xor(lq[j], 32, 64);
  }
  __syncthreads();  // all sH use finished -> sbn aliasing safe
  if (l4 == 0) {
#pragma unroll
    for (int j = 0; j < 8; ++j) {
      sbn[w * 256 + j * 16 + l15] = ls[j];
      sbn[w * 256 + 128 + j * 16 + l15] = lq[j];
    }
  }
  __syncthreads();
  {
    float t = sbn[tid] + sbn[256 + tid] + sbn[512 + tid] + sbn[768 + tid];
    if (tid < 128) atomicAdd(&bnSum[tid], t);
    else atomicAdd(&bnSq[tid - 128], t);
  }
}

// K7: fused BN-finalize + out = h2b*scale + shift + xb. 8 elems/thread.
__global__ __launch_bounds__(256) void k_epi(const u32x4* __restrict__ h2b4,
                                             const u32x4* __restrict__ xb4,
                                             const float* __restrict__ bnSum,
                                             const float* __restrict__ bnSq,
                                             const float* __restrict__ gamma,
                                             const float* __restrict__ beta,
                                             f32x4* __restrict__ out4) {
  __shared__ float ssc[128], ssh[128];
  int tid = threadIdx.x;
  if (tid < 128) {
    float m = bnSum[tid] * (1.0f / NNODES);
    float var = bnSq[tid] * (1.0f / NNODES) - m * m;
    float sc = gamma[tid] * rsqrtf(var + BN_EPS);
    ssc[tid] = sc;
    ssh[tid] = beta[tid] - m * sc;
  }
  __syncthreads();
  long j = (long)blockIdx.x * 256 + tid;  // unit of 8 elems
  int c = (int)((j * 8) & 127);
  u32x4 h = __builtin_nontemporal_load(h2b4 + j);
  u32x4 xr = __builtin_nontemporal_load(xb4 + j);
  f32x4 sa = *(f32x4*)(ssc + c), sb = *(f32x4*)(ssc + c + 4);
  f32x4 fa = *(f32x4*)(ssh + c), fb = *(f32x4*)(ssh + c + 4);
  f32x4 oa, ob;
  oa.x = fmaf(bfLO(h.x), sa.x, fa.x) + bfLO(xr.x);
  oa.y = fmaf(bfHI(h.x), sa.y, fa.y) + bfHI(xr.x);
  oa.z = fmaf(bfLO(h.y), sa.z, fa.z) + bfLO(xr.y);
  oa.w = fmaf(bfHI(h.y), sa.w, fa.w) + bfHI(xr.y);
  ob.x = fmaf(bfLO(h.z), sb.x, fb.x) + bfLO(xr.z);
  ob.y = fmaf(bfHI(h.z), sb.y, fb.y) + bfHI(xr.z);
  ob.z = fmaf(bfLO(h.w), sb.z, fb.z) + bfLO(xr.w);
  ob.w = fmaf(bfHI(h.w), sb.w, fb.w) + bfHI(xr.w);
  __builtin_nontemporal_store(oa, out4 + 2 * j);
  __builtin_nontemporal_store(ob, out4 + 2 * j + 1);
}

extern "C" void kernel_launch(void* const* d_in, const int* in_sizes, int n_in,
                              void* d_out, int out_size, void* d_ws, size_t ws_size,
                              hipStream_t stream) {
  const float* x     = (const float*)d_in[0];
  const int*   e32   = (const int*)d_in[1];
  const float* W1    = (const float*)d_in[2];
  const float* b1    = (const float*)d_in[3];
  const float* W2    = (const float*)d_in[4];
  const float* b2    = (const float*)d_in[5];
  const float* gamma = (const float*)d_in[6];
  const float* beta  = (const float*)d_in[7];
  float* out = (float*)d_out;

  char* ws = (char*)d_ws;
  const size_t BFB = (size_t)NNODES * DD * 2;  // 25.6 MB
  unsigned short* xb  = (unsigned short*)ws;
  unsigned short* h0b = (unsigned short*)(ws + BFB);
  unsigned short* h2b = h0b;  // k_fmm writes h2 in-place over h0b

  int* rowPtr     = (int*)(ws + 3 * BFB);           // [NNODES+4]
  int* edgeSrc    = rowPtr + NNODES + 4;            // [NEDGES]
  unsigned* stage = (unsigned*)(edgeSrc + NEDGES);  // [NEDGES]
  int* cnt        = (int*)(stage + NEDGES);         // [NBUCK*PBLK]
  int* off        = cnt + NBUCK * PBLK;             // [NBUCK*PBLK]
  int* bucketTot  = off + NBUCK * PBLK;             // [128]

  unsigned short* wt1 = (unsigned short*)(bucketTot + 256);
  unsigned short* wt2 = wt1 + 16384;
  float* bnSum = (float*)(wt2 + 16384);
  float* bnSq  = bnSum + 128;

  k_prep<<<6764, 256, 0, stream>>>(x, W1, W2, xb, wt1, wt2, bnSum, e32, cnt);
  k_lscan<<<NBUCK, 256, 0, stream>>>(cnt, off, bucketTot);
  k_ppart<<<PBLK, 256, 0, stream>>>(e32, off, bucketTot, stage);
  k_bucket<<<NBUCK, 256, 0, stream>>>(stage, bucketTot, rowPtr, edgeSrc);
  k_gather<<<25000, 256, 0, stream>>>((const u32x2*)xb, rowPtr, edgeSrc,
                                      (u32x2*)h0b);
  k_fmm<<<FMM_GRID, 256, 0, stream>>>(h0b, wt1, wt2, b1, b2, h2b, bnSum, bnSq);
  k_epi<<<6250, 256, 0, stream>>>((const u32x4*)h2b, (const u32x4*)xb, bnSum,
                                  bnSq, gamma, beta, (f32x4*)out);
}

// Round 10
// 197.614 us; speedup vs baseline: 1.0939x; 1.0939x over previous
//
#include <hip/hip_runtime.h>
#include <math.h>

#define NNODES 100000
#define NEDGES 1600000
#define DD 128
#define BN_EPS 1e-5f

#define NBUCK 98     // ceil(100000/1024)
#define BUCKW 1024   // dsts per bucket (bucket = dst>>10)
#define PBLK 512     // partition blocks
#define PCHUNK 3125  // edges per partition block (512*3125 = 1.6M exact)
#define NTILES 1563  // ceil(100000/64) 64-row MLP tiles
#define FMM_GRID 512

typedef __attribute__((ext_vector_type(8))) short bf16x8;
typedef __attribute__((ext_vector_type(4))) float f32x4;
typedef __attribute__((ext_vector_type(2))) unsigned u32x2;
typedef __attribute__((ext_vector_type(4))) unsigned u32x4;

__device__ __forceinline__ unsigned short f2bf(float f) {  // RNE f32->bf16
  unsigned u = __builtin_bit_cast(unsigned, f);
  u = (u + 0x7fffu + ((u >> 16) & 1u)) >> 16;
  return (unsigned short)u;
}
__device__ __forceinline__ float bfLO(unsigned u) {
  return __builtin_bit_cast(float, u << 16);
}
__device__ __forceinline__ float bfHI(unsigned u) {
  return __builtin_bit_cast(float, u & 0xffff0000u);
}

// ---------------------------------------------------------------------------
// ws layout:
//   xb   [100000][128] bf16   25.6 MB
//   h0b  [100000][128] bf16   (agg; overwritten in-place by h2 in k_fmm)
//   (spare 25.6MB region)
//   rowPtr[100004] | edgeSrc[1.6M] | stage[1.6M] | cnt[98*512] | off[98*512]
//   bucketTot[128] | (pad 128) | wt1[16384] wt2[16384] (bf16) | bnSum/bnSq
// ---------------------------------------------------------------------------

// K1: fused prep. blocks 0-1: W->bf16 transposed+swizzled + zero bn.
// blocks 2..6251: x->bf16. blocks 6252..6763: per-(block,bucket) histogram.
__global__ __launch_bounds__(256) void k_prep(const float* __restrict__ x,
                                              const float* __restrict__ W1,
                                              const float* __restrict__ W2,
                                              unsigned short* __restrict__ xb,
                                              unsigned short* __restrict__ wt1,
                                              unsigned short* __restrict__ wt2,
                                              float* __restrict__ bnAcc,
                                              const int* __restrict__ e32,
                                              int* __restrict__ cnt) {
  __shared__ int sc[NBUCK];
  int bid = blockIdx.x, tid = threadIdx.x;
  if (bid < 2) {
    const float* W = bid ? W2 : W1;
    unsigned short* wt = bid ? wt2 : wt1;
    if (tid < 128) {
      int n = tid;
      for (int k = 0; k < 128; ++k)
        wt[n * 128 + (k ^ ((n & 7) << 3))] = f2bf(W[k * 128 + n]);
    } else {
      bnAcc[(bid ? 0 : 128) + (tid - 128)] = 0.f;  // bnSum / bnSq halves
    }
  } else if (bid < 6252) {  // x -> bf16 : 6250 blocks * 2048 elems
    long j = (long)(bid - 2) * 2048 + tid * 8;
    f32x4 a = __builtin_nontemporal_load((const f32x4*)(x + j));
    f32x4 b = __builtin_nontemporal_load((const f32x4*)(x + j + 4));
    u32x4 o;
    o.x = (unsigned)f2bf(a.x) | ((unsigned)f2bf(a.y) << 16);
    o.y = (unsigned)f2bf(a.z) | ((unsigned)f2bf(a.w) << 16);
    o.z = (unsigned)f2bf(b.x) | ((unsigned)f2bf(b.y) << 16);
    o.w = (unsigned)f2bf(b.z) | ((unsigned)f2bf(b.w) << 16);
    *(u32x4*)(xb + j) = o;
  } else {  // pcount
    int blk = bid - 6252;
    int z = (tid < 64) ? (e32[2 * tid + 1] == 0) : 1;
    int is64 = __syncthreads_and(z);
    for (int i = tid; i < NBUCK; i += 256) sc[i] = 0;
    __syncthreads();
    const int* dstp = is64 ? (e32 + 2 * (long)NEDGES) : (e32 + NEDGES);
    long e0 = (long)blk * PCHUNK;
    for (int i = tid; i < PCHUNK; i += 256) {
      long e = e0 + i;
      int d = is64 ? dstp[2 * e] : dstp[e];
      atomicAdd(&sc[d >> 10], 1);
    }
    __syncthreads();
    for (int i = tid; i < NBUCK; i += 256) cnt[i * PBLK + blk] = sc[i];
  }
}

// K2: per-bucket local scan of 512 block counts -> off (local), bucketTot.
__global__ __launch_bounds__(256) void k_lscan(const int* __restrict__ cnt,
                                               int* __restrict__ off,
                                               int* __restrict__ bucketTot) {
  __shared__ int s[256];
  int b = blockIdx.x, tid = threadIdx.x;
  int v0 = cnt[b * PBLK + 2 * tid], v1 = cnt[b * PBLK + 2 * tid + 1];
  s[tid] = v0 + v1;
  __syncthreads();
  for (int o = 1; o < 256; o <<= 1) {
    int v = (tid >= o) ? s[tid - o] : 0;
    __syncthreads();
    s[tid] += v;
    __syncthreads();
  }
  int excl = s[tid] - v0 - v1;
  off[b * PBLK + 2 * tid] = excl;
  off[b * PBLK + 2 * tid + 1] = excl + v0;
  if (tid == 255) bucketTot[b] = s[255];
}

// K3: partition edges into bucket-major stage, packed (src<<10)|dstLocal.
// Inlines the bucketBase exclusive scan (98 values, cheap per block).
__global__ __launch_bounds__(256) void k_ppart(const int* __restrict__ e32,
                                               const int* __restrict__ off,
                                               const int* __restrict__ bucketTot,
                                               unsigned* __restrict__ stage) {
  __shared__ int cur[NBUCK];
  __shared__ int sbase[128];
  int tid = threadIdx.x, blk = blockIdx.x;
  int z = (tid < 64) ? (e32[2 * tid + 1] == 0) : 1;
  int is64 = __syncthreads_and(z);
  if (tid < 128) sbase[tid] = (tid < NBUCK) ? bucketTot[tid] : 0;
  __syncthreads();
  for (int o = 1; o < 128; o <<= 1) {
    int v = (tid >= o && tid < 128) ? sbase[tid - o] : 0;
    __syncthreads();
    if (tid < 128) sbase[tid] += v;
    __syncthreads();
  }
  if (tid < NBUCK)
    cur[tid] = off[tid * PBLK + blk] + ((tid == 0) ? 0 : sbase[tid - 1]);
  __syncthreads();
  const int* dstp = is64 ? (e32 + 2 * (long)NEDGES) : (e32 + NEDGES);
  long e0 = (long)blk * PCHUNK;
  for (int i = tid; i < PCHUNK; i += 256) {
    long e = e0 + i;
    int d = is64 ? dstp[2 * e] : dstp[e];
    int sv = is64 ? e32[2 * e] : e32[e];
    int pos = atomicAdd(&cur[d >> 10], 1);
    stage[pos] = ((unsigned)sv << 10) | (unsigned)(d & (BUCKW - 1));
  }
}

// K4: one block per bucket: LDS histogram -> scan -> rowPtr; place edgeSrc.
// Inlines bucketBase scan; block 0 sets rowPtr[NNODES].
__global__ __launch_bounds__(256) void k_bucket(const unsigned* __restrict__ stage,
                                                const int* __restrict__ bucketTot,
                                                int* __restrict__ rowPtr,
                                                int* __restrict__ edgeSrc) {
  __shared__ int sdeg[BUCKW];
  __shared__ int srow[BUCKW];
  __shared__ int ss[256];
  __shared__ int sbase[128];
  int b = blockIdx.x, tid = threadIdx.x;
  if (tid < 128) sbase[tid] = (tid < NBUCK) ? bucketTot[tid] : 0;
  for (int i = tid; i < BUCKW; i += 256) sdeg[i] = 0;
  __syncthreads();
  for (int o = 1; o < 128; o <<= 1) {
    int v = (tid >= o && tid < 128) ? sbase[tid - o] : 0;
    __syncthreads();
    if (tid < 128) sbase[tid] += v;
    __syncthreads();
  }
  int base = (b == 0) ? 0 : sbase[b - 1];
  int tot = bucketTot[b];
  if (b == 0 && tid == 0) rowPtr[NNODES] = NEDGES;
  const unsigned* st = stage + base;
  for (int i = tid; i < tot; i += 256) atomicAdd(&sdeg[st[i] & (BUCKW - 1)], 1);
  __syncthreads();
  int j = tid * 4;
  int d0 = sdeg[j], d1 = sdeg[j + 1], d2 = sdeg[j + 2], d3 = sdeg[j + 3];
  int tsum = d0 + d1 + d2 + d3;
  ss[tid] = tsum;
  __syncthreads();
  for (int o = 1; o < 256; o <<= 1) {
    int v = (tid >= o) ? ss[tid - o] : 0;
    __syncthreads();
    ss[tid] += v;
    __syncthreads();
  }
  int excl = ss[tid] - tsum;
  srow[j] = excl;
  srow[j + 1] = excl + d0;
  srow[j + 2] = excl + d0 + d1;
  srow[j + 3] = excl + d0 + d1 + d2;
  __syncthreads();
  for (int i = tid; i < BUCKW; i += 256) {
    int dst = b * BUCKW + i;
    if (dst < NNODES) rowPtr[dst] = base + srow[i];
    sdeg[i] = srow[i];  // reuse as cursor
  }
  __syncthreads();
  for (int i = tid; i < tot; i += 256) {
    unsigned p = st[i];
    int pos = atomicAdd(&sdeg[p & (BUCKW - 1)], 1);
    edgeSrc[base + pos] = (int)(p >> 10);
  }
}

// K5: gather at 8B/lane, 8-edge unrolled (4 independent 512B row-pair loads
// in flight per wave). Wave = 1 node; lanes 0-31 edge e, lanes 32-63 e+1.
__global__ __launch_bounds__(256) void k_gather(const u32x2* __restrict__ xb2,
                                                const int* __restrict__ rowPtr,
                                                const int* __restrict__ edgeSrc,
                                                u32x2* __restrict__ h0b2) {
  int node = (blockIdx.x * 256 + threadIdx.x) >> 6;
  int lane = threadIdx.x & 63;
  if (node >= NNODES) return;
  int li = lane & 31, half = lane >> 5;
  int beg = rowPtr[node], end = rowPtr[node + 1];
  float a0 = 0.f, a1 = 0.f, a2 = 0.f, a3 = 0.f;
  if (half == 0) {  // init from own row
    u32x2 u = xb2[(long)node * 32 + li];
    a0 = bfLO(u.x); a1 = bfHI(u.x); a2 = bfLO(u.y); a3 = bfHI(u.y);
  }
  int e = beg;
  for (; e + 8 <= end; e += 8) {
    int s0 = edgeSrc[e + half];
    int s1 = edgeSrc[e + 2 + half];
    int s2 = edgeSrc[e + 4 + half];
    int s3 = edgeSrc[e + 6 + half];
    u32x2 va = xb2[(long)s0 * 32 + li];
    u32x2 vb = xb2[(long)s1 * 32 + li];
    u32x2 vc = xb2[(long)s2 * 32 + li];
    u32x2 vd = xb2[(long)s3 * 32 + li];
    a0 += bfLO(va.x); a1 += bfHI(va.x); a2 += bfLO(va.y); a3 += bfHI(va.y);
    a0 += bfLO(vb.x); a1 += bfHI(vb.x); a2 += bfLO(vb.y); a3 += bfHI(vb.y);
    a0 += bfLO(vc.x); a1 += bfHI(vc.x); a2 += bfLO(vc.y); a3 += bfHI(vc.y);
    a0 += bfLO(vd.x); a1 += bfHI(vd.x); a2 += bfLO(vd.y); a3 += bfHI(vd.y);
  }
  if (e + 4 <= end) {
    int s0 = edgeSrc[e + half];
    int s1 = edgeSrc[e + 2 + half];
    u32x2 va = xb2[(long)s0 * 32 + li];
    u32x2 vb = xb2[(long)s1 * 32 + li];
    a0 += bfLO(va.x); a1 += bfHI(va.x); a2 += bfLO(va.y); a3 += bfHI(va.y);
    a0 += bfLO(vb.x); a1 += bfHI(vb.x); a2 += bfLO(vb.y); a3 += bfHI(vb.y);
    e += 4;
  }
  if (e + 2 <= end) {
    int s_ = edgeSrc[e + half];
    u32x2 v = xb2[(long)s_ * 32 + li];
    a0 += bfLO(v.x); a1 += bfHI(v.x); a2 += bfLO(v.y); a3 += bfHI(v.y);
    e += 2;
  }
  if (e < end && half == 0) {  // odd tail: lower half only
    int s_ = edgeSrc[e];
    u32x2 v = xb2[(long)s_ * 32 + li];
    a0 += bfLO(v.x); a1 += bfHI(v.x); a2 += bfLO(v.y); a3 += bfHI(v.y);
  }
  a0 += __shfl_xor(a0, 32, 64);
  a1 += __shfl_xor(a1, 32, 64);
  a2 += __shfl_xor(a2, 32, 64);
  a3 += __shfl_xor(a3, 32, 64);
  if (half == 0) {
    u32x2 o;
    o.x = (unsigned)f2bf(a0) | ((unsigned)f2bf(a1) << 16);
    o.y = (unsigned)f2bf(a2) | ((unsigned)f2bf(a3) << 16);
    h0b2[(long)node * 32 + li] = o;
  }
}

// K6: PERSISTENT fused MLP. 512 blocks x 256 thr (2 blocks/CU @ 80KB LDS).
// W1+W2 staged ONCE per block; grid-stride over 1563 64-row tiles.
__global__ __launch_bounds__(256) void k_fmm(const unsigned short* Ab,
                                             const unsigned short* __restrict__ Wt1,
                                             const unsigned short* __restrict__ Wt2,
                                             const float* __restrict__ b1,
                                             const float* __restrict__ b2,
                                             unsigned short* Cb,
                                             float* __restrict__ bnSum,
                                             float* __restrict__ bnSq) {
  __shared__ __align__(16) char smem[81920];
  unsigned short* sW1 = (unsigned short*)smem;           // 32 KB
  unsigned short* sW2 = (unsigned short*)(smem + 32768); // 32 KB
  unsigned short* sH  = (unsigned short*)(smem + 65536); // 16 KB h1 tile
  float* sbn = (float*)(smem + 65536);                   // aliases sH
  int tid = threadIdx.x;
#pragma unroll
  for (int i = 0; i < 8; ++i) {
    ((u32x4*)sW1)[tid + 256 * i] = ((const u32x4*)Wt1)[tid + 256 * i];
    ((u32x4*)sW2)[tid + 256 * i] = ((const u32x4*)Wt2)[tid + 256 * i];
  }
  int w = tid >> 6, lane = tid & 63, l4 = lane >> 4, l15 = lane & 15;
  float bb1[8], bb2[8], ls[8], lq[8];
#pragma unroll
  for (int ni = 0; ni < 8; ++ni) {
    bb1[ni] = b1[ni * 16 + l15];
    bb2[ni] = b2[ni * 16 + l15];
    ls[ni] = 0.f; lq[ni] = 0.f;
  }

  int tile = blockIdx.x;
  bf16x8 af[4];
  {
    int r = tile * 64 + w * 16 + l15;
    if (r > NNODES - 1) r = NNODES - 1;
#pragma unroll
    for (int ks = 0; ks < 4; ++ks)
      af[ks] = __builtin_nontemporal_load(
          (const bf16x8*)(Ab + (long)r * 128 + ks * 32 + l4 * 8));
  }
  __syncthreads();  // W staged

  while (tile < NTILES) {
    int next = tile + FMM_GRID;
    f32x4 acc[8];
#pragma unroll
    for (int ni = 0; ni < 8; ++ni) acc[ni] = (f32x4){0.f, 0.f, 0.f, 0.f};
#pragma unroll
    for (int ks = 0; ks < 4; ++ks)
#pragma unroll
      for (int ni = 0; ni < 8; ++ni) {
        int n = ni * 16 + l15, k = ks * 32 + l4 * 8;
        bf16x8 bf = *(const bf16x8*)(sW1 + n * 128 + (k ^ ((n & 7) << 3)));
        acc[ni] = __builtin_amdgcn_mfma_f32_16x16x32_bf16(af[ks], bf, acc[ni], 0, 0, 0);
      }
    __syncthreads();  // prior iteration's sH readers done -> writable
#pragma unroll
    for (int ni = 0; ni < 8; ++ni) {
      int col = ni * 16 + l15;
#pragma unroll
      for (int rr = 0; rr < 4; ++rr) {
        int row = w * 16 + l4 * 4 + rr;
        float v = fmaxf(acc[ni][rr] + bb1[ni], 0.f);
        sH[row * 128 + (col ^ ((row & 7) << 3))] = f2bf(v);
      }
    }
    __syncthreads();
    bf16x8 afn[4] = {af[0], af[1], af[2], af[3]};
    if (next < NTILES) {  // prefetch next tile's A (overlaps GEMM2)
      int r = next * 64 + w * 16 + l15;
      if (r > NNODES - 1) r = NNODES - 1;
#pragma unroll
      for (int ks = 0; ks < 4; ++ks)
        afn[ks] = __builtin_nontemporal_load(
            (const bf16x8*)(Ab + (long)r * 128 + ks * 32 + l4 * 8));
    }
    bf16x8 a2[4];
    {
      int row = w * 16 + l15;
#pragma unroll
      for (int ks = 0; ks < 4; ++ks) {
        int k = ks * 32 + l4 * 8;
        a2[ks] = *(const bf16x8*)(sH + row * 128 + (k ^ ((row & 7) << 3)));
      }
    }
#pragma unroll
    for (int ni = 0; ni < 8; ++ni) acc[ni] = (f32x4){0.f, 0.f, 0.f, 0.f};
#pragma unroll
    for (int ks = 0; ks < 4; ++ks)
#pragma unroll
      for (int ni = 0; ni < 8; ++ni) {
        int n = ni * 16 + l15, k = ks * 32 + l4 * 8;
        bf16x8 bf = *(const bf16x8*)(sW2 + n * 128 + (k ^ ((n & 7) << 3)));
        acc[ni] = __builtin_amdgcn_mfma_f32_16x16x32_bf16(a2[ks], bf, acc[ni], 0, 0, 0);
      }
#pragma unroll
    for (int ni = 0; ni < 8; ++ni) {
      int n = ni * 16 + l15;
#pragma unroll
      for (int rr = 0; rr < 4; ++rr) {
        int row = tile * 64 + w * 16 + l4 * 4 + rr;
        if (row < NNODES) {
          float v = acc[ni][rr] + bb2[ni];
          __builtin_nontemporal_store(f2bf(v), Cb + (long)row * 128 + n);
          ls[ni] += v; lq[ni] += v * v;
        }
      }
    }
#pragma unroll
    for (int ks = 0; ks < 4; ++ks) af[ks] = afn[ks];
    tile = next;
  }

  // BN: reduce reg partials (cols fixed per thread) -> LDS -> global atomics.
#pragma unroll
  for (int j = 0; j < 8; ++j) {
    ls[j] += __shfl_xor(ls[j], 16, 64); ls[j] += __shfl_xor(ls[j], 32, 64);
    lq[j] += __shfl_xor(lq[j], 16, 64); lq[j] += __shfl_xor(lq[j], 32, 64);
  }
  __syncthreads();  // all sH use finished -> sbn aliasing safe
  if (l4 == 0) {
#pragma unroll
    for (int j = 0; j < 8; ++j) {
      sbn[w * 256 + j * 16 + l15] = ls[j];
      sbn[w * 256 + 128 + j * 16 + l15] = lq[j];
    }
  }
  __syncthreads();
  {
    float t = sbn[tid] + sbn[256 + tid] + sbn[512 + tid] + sbn[768 + tid];
    if (tid < 128) atomicAdd(&bnSum[tid], t);
    else atomicAdd(&bnSq[tid - 128], t);
  }
}

// K7: fused BN-finalize + out = h2b*scale + shift + xb. 8 elems/thread.
__global__ __launch_bounds__(256) void k_epi(const u32x4* __restrict__ h2b4,
                                             const u32x4* __restrict__ xb4,
                                             const float* __restrict__ bnSum,
                                             const float* __restrict__ bnSq,
                                             const float* __restrict__ gamma,
                                             const float* __restrict__ beta,
                                             f32x4* __restrict__ out4) {
  __shared__ float ssc[128], ssh[128];
  int tid = threadIdx.x;
  if (tid < 128) {
    float m = bnSum[tid] * (1.0f / NNODES);
    float var = bnSq[tid] * (1.0f / NNODES) - m * m;
    float sc = gamma[tid] * rsqrtf(var + BN_EPS);
    ssc[tid] = sc;
    ssh[tid] = beta[tid] - m * sc;
  }
  __syncthreads();
  long j = (long)blockIdx.x * 256 + tid;  // unit of 8 elems
  int c = (int)((j * 8) & 127);
  u32x4 h = __builtin_nontemporal_load(h2b4 + j);
  u32x4 xr = __builtin_nontemporal_load(xb4 + j);
  f32x4 sa = *(f32x4*)(ssc + c), sb = *(f32x4*)(ssc + c + 4);
  f32x4 fa = *(f32x4*)(ssh + c), fb = *(f32x4*)(ssh + c + 4);
  f32x4 oa, ob;
  oa.x = fmaf(bfLO(h.x), sa.x, fa.x) + bfLO(xr.x);
  oa.y = fmaf(bfHI(h.x), sa.y, fa.y) + bfHI(xr.x);
  oa.z = fmaf(bfLO(h.y), sa.z, fa.z) + bfLO(xr.y);
  oa.w = fmaf(bfHI(h.y), sa.w, fa.w) + bfHI(xr.y);
  ob.x = fmaf(bfLO(h.z), sb.x, fb.x) + bfLO(xr.z);
  ob.y = fmaf(bfHI(h.z), sb.y, fb.y) + bfHI(xr.z);
  ob.z = fmaf(bfLO(h.w), sb.z, fb.z) + bfLO(xr.w);
  ob.w = fmaf(bfHI(h.w), sb.w, fb.w) + bfHI(xr.w);
  __builtin_nontemporal_store(oa, out4 + 2 * j);
  __builtin_nontemporal_store(ob, out4 + 2 * j + 1);
}

extern "C" void kernel_launch(void* const* d_in, const int* in_sizes, int n_in,
                              void* d_out, int out_size, void* d_ws, size_t ws_size,
                              hipStream_t stream) {
  const float* x     = (const float*)d_in[0];
  const int*   e32   = (const int*)d_in[1];
  const float* W1    = (const float*)d_in[2];
  const float* b1    = (const float*)d_in[3];
  const float* W2    = (const float*)d_in[4];
  const float* b2    = (const float*)d_in[5];
  const float* gamma = (const float*)d_in[6];
  const float* beta  = (const float*)d_in[7];
  float* out = (float*)d_out;

  char* ws = (char*)d_ws;
  const size_t BFB = (size_t)NNODES * DD * 2;  // 25.6 MB
  unsigned short* xb  = (unsigned short*)ws;
  unsigned short* h0b = (unsigned short*)(ws + BFB);
  unsigned short* h2b = h0b;  // k_fmm writes h2 in-place over h0b

  int* rowPtr     = (int*)(ws + 3 * BFB);           // [NNODES+4]
  int* edgeSrc    = rowPtr + NNODES + 4;            // [NEDGES]
  unsigned* stage = (unsigned*)(edgeSrc + NEDGES);  // [NEDGES]
  int* cnt        = (int*)(stage + NEDGES);         // [NBUCK*PBLK]
  int* off        = cnt + NBUCK * PBLK;             // [NBUCK*PBLK]
  int* bucketTot  = off + NBUCK * PBLK;             // [128]

  unsigned short* wt1 = (unsigned short*)(bucketTot + 256);
  unsigned short* wt2 = wt1 + 16384;
  float* bnSum = (float*)(wt2 + 16384);
  float* bnSq  = bnSum + 128;

  k_prep<<<6764, 256, 0, stream>>>(x, W1, W2, xb, wt1, wt2, bnSum, e32, cnt);
  k_lscan<<<NBUCK, 256, 0, stream>>>(cnt, off, bucketTot);
  k_ppart<<<PBLK, 256, 0, stream>>>(e32, off, bucketTot, stage);
  k_bucket<<<NBUCK, 256, 0, stream>>>(stage, bucketTot, rowPtr, edgeSrc);
  k_gather<<<25000, 256, 0, stream>>>((const u32x2*)xb, rowPtr, edgeSrc,
                                      (u32x2*)h0b);
  k_fmm<<<FMM_GRID, 256, 0, stream>>>(h0b, wt1, wt2, b1, b2, h2b, bnSum, bnSq);
  k_epi<<<6250, 256, 0, stream>>>((const u32x4*)h2b, (const u32x4*)xb, bnSum,
                                  bnSq, gamma, beta, (f32x4*)out);
}

// Round 11
// 195.974 us; speedup vs baseline: 1.1031x; 1.0084x over previous
//
#include <hip/hip_runtime.h>
#include <math.h>

#define NNODES 100000
#define NEDGES 1600000
#define DD 128
#define BN_EPS 1e-5f

#define NBUCK 98     // ceil(100000/1024)
#define BUCKW 1024   // dsts per bucket (bucket = dst>>10)
#define PBLK 512     // partition blocks
#define PCHUNK 3125  // edges per partition block (512*3125 = 1.6M exact)
#define NTILES 1563  // ceil(100000/64) 64-row MLP tiles
#define FMM_GRID 512

typedef __attribute__((ext_vector_type(8))) short bf16x8;
typedef __attribute__((ext_vector_type(4))) float f32x4;
typedef __attribute__((ext_vector_type(2))) unsigned u32x2;
typedef __attribute__((ext_vector_type(4))) unsigned u32x4;

__device__ __forceinline__ unsigned short f2bf(float f) {  // RNE f32->bf16
  unsigned u = __builtin_bit_cast(unsigned, f);
  u = (u + 0x7fffu + ((u >> 16) & 1u)) >> 16;
  return (unsigned short)u;
}
__device__ __forceinline__ float bfLO(unsigned u) {
  return __builtin_bit_cast(float, u << 16);
}
__device__ __forceinline__ float bfHI(unsigned u) {
  return __builtin_bit_cast(float, u & 0xffff0000u);
}

// ---------------------------------------------------------------------------
// ws layout:
//   xb   [100000][128] bf16   25.6 MB
//   h0b  [100000][128] bf16   (agg; overwritten in-place by h2 in k_fmm)
//   (spare 25.6MB region)
//   rowPtr[100004] | edgeSrc[1.6M] | stage[1.6M] | cnt[98*512] | off[98*512]
//   bucketTot[128] | (pad 128) | wt1[16384] wt2[16384] (bf16) | bnSum/bnSq
// ---------------------------------------------------------------------------

// K1: fused prep. blocks 0-1: W->bf16 transposed+swizzled + zero bn.
// blocks 2..6251: x->bf16. blocks 6252..6763: per-(block,bucket) histogram.
__global__ __launch_bounds__(256) void k_prep(const float* __restrict__ x,
                                              const float* __restrict__ W1,
                                              const float* __restrict__ W2,
                                              unsigned short* __restrict__ xb,
                                              unsigned short* __restrict__ wt1,
                                              unsigned short* __restrict__ wt2,
                                              float* __restrict__ bnAcc,
                                              const int* __restrict__ e32,
                                              int* __restrict__ cnt) {
  __shared__ int sc[NBUCK];
  int bid = blockIdx.x, tid = threadIdx.x;
  if (bid < 2) {
    const float* W = bid ? W2 : W1;
    unsigned short* wt = bid ? wt2 : wt1;
    if (tid < 128) {
      int n = tid;
      for (int k = 0; k < 128; ++k)
        wt[n * 128 + (k ^ ((n & 7) << 3))] = f2bf(W[k * 128 + n]);
    } else {
      bnAcc[(bid ? 0 : 128) + (tid - 128)] = 0.f;  // bnSum / bnSq halves
    }
  } else if (bid < 6252) {  // x -> bf16 : 6250 blocks * 2048 elems
    long j = (long)(bid - 2) * 2048 + tid * 8;
    f32x4 a = __builtin_nontemporal_load((const f32x4*)(x + j));
    f32x4 b = __builtin_nontemporal_load((const f32x4*)(x + j + 4));
    u32x4 o;
    o.x = (unsigned)f2bf(a.x) | ((unsigned)f2bf(a.y) << 16);
    o.y = (unsigned)f2bf(a.z) | ((unsigned)f2bf(a.w) << 16);
    o.z = (unsigned)f2bf(b.x) | ((unsigned)f2bf(b.y) << 16);
    o.w = (unsigned)f2bf(b.z) | ((unsigned)f2bf(b.w) << 16);
    *(u32x4*)(xb + j) = o;
  } else {  // pcount
    int blk = bid - 6252;
    int z = (tid < 64) ? (e32[2 * tid + 1] == 0) : 1;
    int is64 = __syncthreads_and(z);
    for (int i = tid; i < NBUCK; i += 256) sc[i] = 0;
    __syncthreads();
    const int* dstp = is64 ? (e32 + 2 * (long)NEDGES) : (e32 + NEDGES);
    long e0 = (long)blk * PCHUNK;
    for (int i = tid; i < PCHUNK; i += 256) {
      long e = e0 + i;
      int d = is64 ? dstp[2 * e] : dstp[e];
      atomicAdd(&sc[d >> 10], 1);
    }
    __syncthreads();
    for (int i = tid; i < NBUCK; i += 256) cnt[i * PBLK + blk] = sc[i];
  }
}

// K2: per-bucket local scan of 512 block counts -> off (local), bucketTot.
__global__ __launch_bounds__(256) void k_lscan(const int* __restrict__ cnt,
                                               int* __restrict__ off,
                                               int* __restrict__ bucketTot) {
  __shared__ int s[256];
  int b = blockIdx.x, tid = threadIdx.x;
  int v0 = cnt[b * PBLK + 2 * tid], v1 = cnt[b * PBLK + 2 * tid + 1];
  s[tid] = v0 + v1;
  __syncthreads();
  for (int o = 1; o < 256; o <<= 1) {
    int v = (tid >= o) ? s[tid - o] : 0;
    __syncthreads();
    s[tid] += v;
    __syncthreads();
  }
  int excl = s[tid] - v0 - v1;
  off[b * PBLK + 2 * tid] = excl;
  off[b * PBLK + 2 * tid + 1] = excl + v0;
  if (tid == 255) bucketTot[b] = s[255];
}

// K3: partition edges into bucket-major stage, packed (src<<10)|dstLocal.
// Inlines the bucketBase exclusive scan (98 values, cheap per block).
__global__ __launch_bounds__(256) void k_ppart(const int* __restrict__ e32,
                                               const int* __restrict__ off,
                                               const int* __restrict__ bucketTot,
                                               unsigned* __restrict__ stage) {
  __shared__ int cur[NBUCK];
  __shared__ int sbase[128];
  int tid = threadIdx.x, blk = blockIdx.x;
  int z = (tid < 64) ? (e32[2 * tid + 1] == 0) : 1;
  int is64 = __syncthreads_and(z);
  if (tid < 128) sbase[tid] = (tid < NBUCK) ? bucketTot[tid] : 0;
  __syncthreads();
  for (int o = 1; o < 128; o <<= 1) {
    int v = (tid >= o && tid < 128) ? sbase[tid - o] : 0;
    __syncthreads();
    if (tid < 128) sbase[tid] += v;
    __syncthreads();
  }
  if (tid < NBUCK)
    cur[tid] = off[tid * PBLK + blk] + ((tid == 0) ? 0 : sbase[tid - 1]);
  __syncthreads();
  const int* dstp = is64 ? (e32 + 2 * (long)NEDGES) : (e32 + NEDGES);
  long e0 = (long)blk * PCHUNK;
  for (int i = tid; i < PCHUNK; i += 256) {
    long e = e0 + i;
    int d = is64 ? dstp[2 * e] : dstp[e];
    int sv = is64 ? e32[2 * e] : e32[e];
    int pos = atomicAdd(&cur[d >> 10], 1);
    stage[pos] = ((unsigned)sv << 10) | (unsigned)(d & (BUCKW - 1));
  }
}

// K4: one block per bucket: LDS histogram -> scan -> rowPtr; place edgeSrc.
// Inlines bucketBase scan; block 0 sets rowPtr[NNODES].
__global__ __launch_bounds__(256) void k_bucket(const unsigned* __restrict__ stage,
                                                const int* __restrict__ bucketTot,
                                                int* __restrict__ rowPtr,
                                                int* __restrict__ edgeSrc) {
  __shared__ int sdeg[BUCKW];
  __shared__ int srow[BUCKW];
  __shared__ int ss[256];
  __shared__ int sbase[128];
  int b = blockIdx.x, tid = threadIdx.x;
  if (tid < 128) sbase[tid] = (tid < NBUCK) ? bucketTot[tid] : 0;
  for (int i = tid; i < BUCKW; i += 256) sdeg[i] = 0;
  __syncthreads();
  for (int o = 1; o < 128; o <<= 1) {
    int v = (tid >= o && tid < 128) ? sbase[tid - o] : 0;
    __syncthreads();
    if (tid < 128) sbase[tid] += v;
    __syncthreads();
  }
  int base = (b == 0) ? 0 : sbase[b - 1];
  int tot = bucketTot[b];
  if (b == 0 && tid == 0) rowPtr[NNODES] = NEDGES;
  const unsigned* st = stage + base;
  for (int i = tid; i < tot; i += 256) atomicAdd(&sdeg[st[i] & (BUCKW - 1)], 1);
  __syncthreads();
  int j = tid * 4;
  int d0 = sdeg[j], d1 = sdeg[j + 1], d2 = sdeg[j + 2], d3 = sdeg[j + 3];
  int tsum = d0 + d1 + d2 + d3;
  ss[tid] = tsum;
  __syncthreads();
  for (int o = 1; o < 256; o <<= 1) {
    int v = (tid >= o) ? ss[tid - o] : 0;
    __syncthreads();
    ss[tid] += v;
    __syncthreads();
  }
  int excl = ss[tid] - tsum;
  srow[j] = excl;
  srow[j + 1] = excl + d0;
  srow[j + 2] = excl + d0 + d1;
  srow[j + 3] = excl + d0 + d1 + d2;
  __syncthreads();
  for (int i = tid; i < BUCKW; i += 256) {
    int dst = b * BUCKW + i;
    if (dst < NNODES) rowPtr[dst] = base + srow[i];
    sdeg[i] = srow[i];  // reuse as cursor
  }
  __syncthreads();
  for (int i = tid; i < tot; i += 256) {
    unsigned p = st[i];
    int pos = atomicAdd(&sdeg[p & (BUCKW - 1)], 1);
    edgeSrc[base + pos] = (int)(p >> 10);
  }
}

// K5: gather at 16B/lane. Wave = 1 node; 16 lanes per row, quarter q = lane>>4
// handles edge e+q. 16-edge unroll = 4 x 1KB loads in flight per wave.
__global__ __launch_bounds__(256) void k_gather(const u32x4* __restrict__ xb4,
                                                const int* __restrict__ rowPtr,
                                                const int* __restrict__ edgeSrc,
                                                u32x4* __restrict__ h0b4) {
  int node = (blockIdx.x * 256 + threadIdx.x) >> 6;
  int lane = threadIdx.x & 63;
  if (node >= NNODES) return;
  int li = lane & 15, q = lane >> 4;
  int beg = rowPtr[node], end = rowPtr[node + 1];
  float a0 = 0.f, a1 = 0.f, a2 = 0.f, a3 = 0.f;
  float a4 = 0.f, a5 = 0.f, a6 = 0.f, a7 = 0.f;
#define ACC8(v)                                              \
  a0 += bfLO((v).x); a1 += bfHI((v).x);                      \
  a2 += bfLO((v).y); a3 += bfHI((v).y);                      \
  a4 += bfLO((v).z); a5 += bfHI((v).z);                      \
  a6 += bfLO((v).w); a7 += bfHI((v).w);
  if (q == 0) {  // init from own row
    u32x4 u = xb4[(long)node * 16 + li];
    ACC8(u)
  }
  int e = beg;
  for (; e + 16 <= end; e += 16) {
    int s0 = edgeSrc[e + q];
    int s1 = edgeSrc[e + 4 + q];
    int s2 = edgeSrc[e + 8 + q];
    int s3 = edgeSrc[e + 12 + q];
    u32x4 v0 = xb4[(long)s0 * 16 + li];
    u32x4 v1 = xb4[(long)s1 * 16 + li];
    u32x4 v2 = xb4[(long)s2 * 16 + li];
    u32x4 v3 = xb4[(long)s3 * 16 + li];
    ACC8(v0) ACC8(v1) ACC8(v2) ACC8(v3)
  }
  if (e + 8 <= end) {
    int s0 = edgeSrc[e + q];
    int s1 = edgeSrc[e + 4 + q];
    u32x4 v0 = xb4[(long)s0 * 16 + li];
    u32x4 v1 = xb4[(long)s1 * 16 + li];
    ACC8(v0) ACC8(v1)
    e += 8;
  }
  for (; e < end; e += 4) {  // predicated 4-edge tail chunks
    if (q < end - e) {
      int s = edgeSrc[e + q];
      u32x4 v = xb4[(long)s * 16 + li];
      ACC8(v)
    }
  }
#undef ACC8
  a0 += __shfl_xor(a0, 16, 64); a0 += __shfl_xor(a0, 32, 64);
  a1 += __shfl_xor(a1, 16, 64); a1 += __shfl_xor(a1, 32, 64);
  a2 += __shfl_xor(a2, 16, 64); a2 += __shfl_xor(a2, 32, 64);
  a3 += __shfl_xor(a3, 16, 64); a3 += __shfl_xor(a3, 32, 64);
  a4 += __shfl_xor(a4, 16, 64); a4 += __shfl_xor(a4, 32, 64);
  a5 += __shfl_xor(a5, 16, 64); a5 += __shfl_xor(a5, 32, 64);
  a6 += __shfl_xor(a6, 16, 64); a6 += __shfl_xor(a6, 32, 64);
  a7 += __shfl_xor(a7, 16, 64); a7 += __shfl_xor(a7, 32, 64);
  if (q == 0) {
    u32x4 o;
    o.x = (unsigned)f2bf(a0) | ((unsigned)f2bf(a1) << 16);
    o.y = (unsigned)f2bf(a2) | ((unsigned)f2bf(a3) << 16);
    o.z = (unsigned)f2bf(a4) | ((unsigned)f2bf(a5) << 16);
    o.w = (unsigned)f2bf(a6) | ((unsigned)f2bf(a7) << 16);
    h0b4[(long)node * 16 + li] = o;
  }
}

// K6: PERSISTENT fused MLP. 512 blocks x 256 thr (2 blocks/CU @ 80KB LDS).
// W1+W2 staged ONCE per block; grid-stride over 1563 64-row tiles.
__global__ __launch_bounds__(256) void k_fmm(const unsigned short* Ab,
                                             const unsigned short* __restrict__ Wt1,
                                             const unsigned short* __restrict__ Wt2,
                                             const float* __restrict__ b1,
                                             const float* __restrict__ b2,
                                             unsigned short* Cb,
                                             float* __restrict__ bnSum,
                                             float* __restrict__ bnSq) {
  __shared__ __align__(16) char smem[81920];
  unsigned short* sW1 = (unsigned short*)smem;           // 32 KB
  unsigned short* sW2 = (unsigned short*)(smem + 32768); // 32 KB
  unsigned short* sH  = (unsigned short*)(smem + 65536); // 16 KB h1 tile
  float* sbn = (float*)(smem + 65536);                   // aliases sH
  int tid = threadIdx.x;
#pragma unroll
  for (int i = 0; i < 8; ++i) {
    ((u32x4*)sW1)[tid + 256 * i] = ((const u32x4*)Wt1)[tid + 256 * i];
    ((u32x4*)sW2)[tid + 256 * i] = ((const u32x4*)Wt2)[tid + 256 * i];
  }
  int w = tid >> 6, lane = tid & 63, l4 = lane >> 4, l15 = lane & 15;
  float bb1[8], bb2[8], ls[8], lq[8];
#pragma unroll
  for (int ni = 0; ni < 8; ++ni) {
    bb1[ni] = b1[ni * 16 + l15];
    bb2[ni] = b2[ni * 16 + l15];
    ls[ni] = 0.f; lq[ni] = 0.f;
  }

  int tile = blockIdx.x;
  bf16x8 af[4];
  {
    int r = tile * 64 + w * 16 + l15;
    if (r > NNODES - 1) r = NNODES - 1;
#pragma unroll
    for (int ks = 0; ks < 4; ++ks)
      af[ks] = __builtin_nontemporal_load(
          (const bf16x8*)(Ab + (long)r * 128 + ks * 32 + l4 * 8));
  }
  __syncthreads();  // W staged

  while (tile < NTILES) {
    int next = tile + FMM_GRID;
    f32x4 acc[8];
#pragma unroll
    for (int ni = 0; ni < 8; ++ni) acc[ni] = (f32x4){0.f, 0.f, 0.f, 0.f};
#pragma unroll
    for (int ks = 0; ks < 4; ++ks)
#pragma unroll
      for (int ni = 0; ni < 8; ++ni) {
        int n = ni * 16 + l15, k = ks * 32 + l4 * 8;
        bf16x8 bf = *(const bf16x8*)(sW1 + n * 128 + (k ^ ((n & 7) << 3)));
        acc[ni] = __builtin_amdgcn_mfma_f32_16x16x32_bf16(af[ks], bf, acc[ni], 0, 0, 0);
      }
    __syncthreads();  // prior iteration's sH readers done -> writable
#pragma unroll
    for (int ni = 0; ni < 8; ++ni) {
      int col = ni * 16 + l15;
#pragma unroll
      for (int rr = 0; rr < 4; ++rr) {
        int row = w * 16 + l4 * 4 + rr;
        float v = fmaxf(acc[ni][rr] + bb1[ni], 0.f);
        sH[row * 128 + (col ^ ((row & 7) << 3))] = f2bf(v);
      }
    }
    __syncthreads();
    bf16x8 afn[4] = {af[0], af[1], af[2], af[3]};
    if (next < NTILES) {  // prefetch next tile's A (overlaps GEMM2)
      int r = next * 64 + w * 16 + l15;
      if (r > NNODES - 1) r = NNODES - 1;
#pragma unroll
      for (int ks = 0; ks < 4; ++ks)
        afn[ks] = __builtin_nontemporal_load(
            (const bf16x8*)(Ab + (long)r * 128 + ks * 32 + l4 * 8));
    }
    bf16x8 a2[4];
    {
      int row = w * 16 + l15;
#pragma unroll
      for (int ks = 0; ks < 4; ++ks) {
        int k = ks * 32 + l4 * 8;
        a2[ks] = *(const bf16x8*)(sH + row * 128 + (k ^ ((row & 7) << 3)));
      }
    }
#pragma unroll
    for (int ni = 0; ni < 8; ++ni) acc[ni] = (f32x4){0.f, 0.f, 0.f, 0.f};
#pragma unroll
    for (int ks = 0; ks < 4; ++ks)
#pragma unroll
      for (int ni = 0; ni < 8; ++ni) {
        int n = ni * 16 + l15, k = ks * 32 + l4 * 8;
        bf16x8 bf = *(const bf16x8*)(sW2 + n * 128 + (k ^ ((n & 7) << 3)));
        acc[ni] = __builtin_amdgcn_mfma_f32_16x16x32_bf16(a2[ks], bf, acc[ni], 0, 0, 0);
      }
#pragma unroll
    for (int ni = 0; ni < 8; ++ni) {
      int n = ni * 16 + l15;
#pragma unroll
      for (int rr = 0; rr < 4; ++rr) {
        int row = tile * 64 + w * 16 + l4 * 4 + rr;
        if (row < NNODES) {
          float v = acc[ni][rr] + bb2[ni];
          __builtin_nontemporal_store(f2bf(v), Cb + (long)row * 128 + n);
          ls[ni] += v; lq[ni] += v * v;
        }
      }
    }
#pragma unroll
    for (int ks = 0; ks < 4; ++ks) af[ks] = afn[ks];
    tile = next;
  }

  // BN: reduce reg partials (cols fixed per thread) -> LDS -> global atomics.
#pragma unroll
  for (int j = 0; j < 8; ++j) {
    ls[j] += __shfl_xor(ls[j], 16, 64); ls[j] += __shfl_xor(ls[j], 32, 64);
    lq[j] += __shfl_xor(lq[j], 16, 64); lq[j] += __shfl_xor(lq[j], 32, 64);
  }
  __syncthreads();  // all sH use finished -> sbn aliasing safe
  if (l4 == 0) {
#pragma unroll
    for (int j = 0; j < 8; ++j) {
      sbn[w * 256 + j * 16 + l15] = ls[j];
      sbn[w * 256 + 128 + j * 16 + l15] = lq[j];
    }
  }
  __syncthreads();
  {
    float t = sbn[tid] + sbn[256 + tid] + sbn[512 + tid] + sbn[768 + tid];
    if (tid < 128) atomicAdd(&bnSum[tid], t);
    else atomicAdd(&bnSq[tid - 128], t);
  }
}

// K7: fused BN-finalize + out = h2b*scale + shift + xb. 8 elems/thread.
__global__ __launch_bounds__(256) void k_epi(const u32x4* __restrict__ h2b4,
                                             const u32x4* __restrict__ xb4,
                                             const float* __restrict__ bnSum,
                                             const float* __restrict__ bnSq,
                                             const float* __restrict__ gamma,
                                             const float* __restrict__ beta,
                                             f32x4* __restrict__ out4) {
  __shared__ float ssc[128], ssh[128];
  int tid = threadIdx.x;
  if (tid < 128) {
    float m = bnSum[tid] * (1.0f / NNODES);
    float var = bnSq[tid] * (1.0f / NNODES) - m * m;
    float sc = gamma[tid] * rsqrtf(var + BN_EPS);
    ssc[tid] = sc;
    ssh[tid] = beta[tid] - m * sc;
  }
  __syncthreads();
  long j = (long)blockIdx.x * 256 + tid;  // unit of 8 elems
  int c = (int)((j * 8) & 127);
  u32x4 h = __builtin_nontemporal_load(h2b4 + j);
  u32x4 xr = __builtin_nontemporal_load(xb4 + j);
  f32x4 sa = *(f32x4*)(ssc + c), sb = *(f32x4*)(ssc + c + 4);
  f32x4 fa = *(f32x4*)(ssh + c), fb = *(f32x4*)(ssh + c + 4);
  f32x4 oa, ob;
  oa.x = fmaf(bfLO(h.x), sa.x, fa.x) + bfLO(xr.x);
  oa.y = fmaf(bfHI(h.x), sa.y, fa.y) + bfHI(xr.x);
  oa.z = fmaf(bfLO(h.y), sa.z, fa.z) + bfLO(xr.y);
  oa.w = fmaf(bfHI(h.y), sa.w, fa.w) + bfHI(xr.y);
  ob.x = fmaf(bfLO(h.z), sb.x, fb.x) + bfLO(xr.z);
  ob.y = fmaf(bfHI(h.z), sb.y, fb.y) + bfHI(xr.z);
  ob.z = fmaf(bfLO(h.w), sb.z, fb.z) + bfLO(xr.w);
  ob.w = fmaf(bfHI(h.w), sb.w, fb.w) + bfHI(xr.w);
  __builtin_nontemporal_store(oa, out4 + 2 * j);
  __builtin_nontemporal_store(ob, out4 + 2 * j + 1);
}

extern "C" void kernel_launch(void* const* d_in, const int* in_sizes, int n_in,
                              void* d_out, int out_size, void* d_ws, size_t ws_size,
                              hipStream_t stream) {
  const float* x     = (const float*)d_in[0];
  const int*   e32   = (const int*)d_in[1];
  const float* W1    = (const float*)d_in[2];
  const float* b1    = (const float*)d_in[3];
  const float* W2    = (const float*)d_in[4];
  const float* b2    = (const float*)d_in[5];
  const float* gamma = (const float*)d_in[6];
  const float* beta  = (const float*)d_in[7];
  float* out = (float*)d_out;

  char* ws = (char*)d_ws;
  const size_t BFB = (size_t)NNODES * DD * 2;  // 25.6 MB
  unsigned short* xb  = (unsigned short*)ws;
  unsigned short* h0b = (unsigned short*)(ws + BFB);
  unsigned short* h2b = h0b;  // k_fmm writes h2 in-place over h0b

  int* rowPtr     = (int*)(ws + 3 * BFB);           // [NNODES+4]
  int* edgeSrc    = rowPtr + NNODES + 4;            // [NEDGES]
  unsigned* stage = (unsigned*)(edgeSrc + NEDGES);  // [NEDGES]
  int* cnt        = (int*)(stage + NEDGES);         // [NBUCK*PBLK]
  int* off        = cnt + NBUCK * PBLK;             // [NBUCK*PBLK]
  int* bucketTot  = off + NBUCK * PBLK;             // [128]

  unsigned short* wt1 = (unsigned short*)(bucketTot + 256);
  unsigned short* wt2 = wt1 + 16384;
  float* bnSum = (float*)(wt2 + 16384);
  float* bnSq  = bnSum + 128;

  k_prep<<<6764, 256, 0, stream>>>(x, W1, W2, xb, wt1, wt2, bnSum, e32, cnt);
  k_lscan<<<NBUCK, 256, 0, stream>>>(cnt, off, bucketTot);
  k_ppart<<<PBLK, 256, 0, stream>>>(e32, off, bucketTot, stage);
  k_bucket<<<NBUCK, 256, 0, stream>>>(stage, bucketTot, rowPtr, edgeSrc);
  k_gather<<<25000, 256, 0, stream>>>((const u32x4*)xb, rowPtr, edgeSrc,
                                      (u32x4*)h0b);
  k_fmm<<<FMM_GRID, 256, 0, stream>>>(h0b, wt1, wt2, b1, b2, h2b, bnSum, bnSq);
  k_epi<<<6250, 256, 0, stream>>>((const u32x4*)h2b, (const u32x4*)xb, bnSum,
                                  bnSq, gamma, beta, (f32x4*)out);
}